// Round 7
// baseline (255.722 us; speedup 1.0000x reference)
//
#include <hip/hip_runtime.h>
#include <math.h>

#define NB 8
#define NQ 100
#define NQH 50
#define NCP1 3
#define NC 2
#define HIN 128
#define WIN 128
#define HOUT 512
#define WOUT 512
#define QSTR (HIN * WIN)

#if __has_builtin(__builtin_amdgcn_exp2f)
#define EXP2F(x) __builtin_amdgcn_exp2f(x)
#else
#define EXP2F(x) exp2f(x)
#endif
#if __has_builtin(__builtin_amdgcn_rcpf)
#define RCPF(x) __builtin_amdgcn_rcpf(x)
#else
#define RCPF(x) (1.0f / (x))
#endif

__device__ __forceinline__ float bperm(int byteaddr, float v) {
  return __int_as_float(__builtin_amdgcn_ds_bpermute(byteaddr, __float_as_int(v)));
}

// R7: R6's wave-per-row structure (2 coalesced float2 loads/q, halo via
// ds_bpermute, depth-4 pipeline) + in-block q-split for 2x TLP:
// 512 threads = 8 waves; wave w = row-phase r=w&3, q-half qh=w>>2 (50 q each).
// Total issue unchanged; waves/SIMD 4 -> 8 (32/CU = max) to cover the 37%
// stall R6 left.  q-half partials combined through 16KB LDS (conflict-free
// SoA, one extra barrier) — no 2nd kernel, no extra HBM traffic.
__global__ __launch_bounds__(512, 8)
void m2f_fused(const float* __restrict__ cls,
               const float* __restrict__ masks,
               float* __restrict__ out) {
  const int k   = blockIdx.x;   // 0..127
  const int b   = blockIdx.y;   // 0..7
  const int tid = threadIdx.x;  // 0..511

  __shared__ float2 pq[NQ];           // (p_class0, p_class1) per q
  __shared__ float  part[16][256];    // qh=1 partials: [j][r*64+lane]

  // ---- inline class softmax (keep first NC of NCP1) ----
  if (tid < NQ) {
    const float* cl = cls + (b * NQ + tid) * NCP1;
    float a0 = cl[0], a1 = cl[1], a2 = cl[2];
    float mx = fmaxf(a0, fmaxf(a1, a2));
    const float L2E = 1.4426950408889634f;
    float e0 = EXP2F((a0 - mx) * L2E);
    float e1 = EXP2F((a1 - mx) * L2E);
    float e2 = EXP2F((a2 - mx) * L2E);
    float inv = RCPF(e0 + e1 + e2);
    pq[tid] = make_float2(e0 * inv, e1 * inv);
  }
  __syncthreads();

  const int wave = tid >> 6;    // 0..7
  const int r    = wave & 3;    // output row phase (y = 4k+r)
  const int qh   = wave >> 2;   // q half: 0 -> q 0..49, 1 -> q 50..99
  const int lane = tid & 63;    // col group: x = 8*lane .. 8*lane+7
  const int q0   = qh * NQH;

  // clamped input rows + vertical weights (pre-scaled by -log2e so
  // sigmoid(x) = rcp(1 + exp2(v)), v = -log2e * x)
  const int rlo = (r < 2) ? (k > 0 ? k - 1 : 0) : k;
  const int rhi = (r < 2) ? k : (k < HIN - 1 ? k + 1 : HIN - 1);
  const float NL2E = -1.4426950408889634f;
  const float wlo = ((r == 0) ? 0.375f : (r == 1) ? 0.125f
                   : (r == 2) ? 0.875f : 0.625f) * NL2E;
  const float whi = ((r == 0) ? 0.625f : (r == 1) ? 0.875f
                   : (r == 2) ? 0.125f : 0.375f) * NL2E;

  const int oA = rlo * WIN + 2 * lane;
  const int oB = rhi * WIN + 2 * lane;
  const float* __restrict__ base = masks + (size_t)b * NQ * QSTR;  // uniform

  const int addrL = (lane - 1) << 2;
  const int addrR = (lane + 1) << 2;
  const bool edgeL = (lane == 0);
  const bool edgeR = (lane == 63);

  float c0[8], c1[8];
#pragma unroll
  for (int j = 0; j < 8; ++j) { c0[j] = 0.f; c1[j] = 0.f; }

  // depth-4 pipeline: 2 x float2 per stage
  float2 A0, B0, A1, B1, A2, B2, A3, B3;

#define LOADSET(S, qq)                                                    \
  do {                                                                    \
    const float* mq = base + (size_t)(qq) * QSTR; /* uniform SGPR adv */  \
    A##S = *(const float2*)(mq + oA);                                     \
    B##S = *(const float2*)(mq + oB);                                     \
  } while (0)

#define COMPUTE(S, qq)                                                    \
  do {                                                                    \
    const float2 pd = pq[qq];                                             \
    float t0 = fmaf(wlo, A##S.x, whi * B##S.x);   /* col 2c   */          \
    float t1 = fmaf(wlo, A##S.y, whi * B##S.y);   /* col 2c+1 */          \
    float tLr = bperm(addrL, t1);                                         \
    float tRr = bperm(addrR, t0);                                         \
    float tL = edgeL ? t0 : tLr;                                          \
    float tR = edgeR ? t1 : tRr;                                          \
    float dm = tL - t0, dd = t1 - t0, dp = tR - t1;                       \
    float v0 = fmaf(0.375f, dm, t0);                                      \
    float v1 = fmaf(0.125f, dm, t0);                                      \
    float v2 = fmaf(0.125f, dd, t0);                                      \
    float v3 = fmaf(0.375f, dd, t0);                                      \
    float v4 = fmaf(0.625f, dd, t0);                                      \
    float v5 = fmaf(0.875f, dd, t0);                                      \
    float v6 = fmaf(0.125f, dp, t1);                                      \
    float v7 = fmaf(0.375f, dp, t1);                                      \
    float s0 = RCPF(1.0f + EXP2F(v0));                                    \
    float s1 = RCPF(1.0f + EXP2F(v1));                                    \
    float s2 = RCPF(1.0f + EXP2F(v2));                                    \
    float s3 = RCPF(1.0f + EXP2F(v3));                                    \
    float s4 = RCPF(1.0f + EXP2F(v4));                                    \
    float s5 = RCPF(1.0f + EXP2F(v5));                                    \
    float s6 = RCPF(1.0f + EXP2F(v6));                                    \
    float s7 = RCPF(1.0f + EXP2F(v7));                                    \
    c0[0] = fmaf(pd.x, s0, c0[0]);  c1[0] = fmaf(pd.y, s0, c1[0]);        \
    c0[1] = fmaf(pd.x, s1, c0[1]);  c1[1] = fmaf(pd.y, s1, c1[1]);        \
    c0[2] = fmaf(pd.x, s2, c0[2]);  c1[2] = fmaf(pd.y, s2, c1[2]);        \
    c0[3] = fmaf(pd.x, s3, c0[3]);  c1[3] = fmaf(pd.y, s3, c1[3]);        \
    c0[4] = fmaf(pd.x, s4, c0[4]);  c1[4] = fmaf(pd.y, s4, c1[4]);        \
    c0[5] = fmaf(pd.x, s5, c0[5]);  c1[5] = fmaf(pd.y, s5, c1[5]);        \
    c0[6] = fmaf(pd.x, s6, c0[6]);  c1[6] = fmaf(pd.y, s6, c1[6]);        \
    c0[7] = fmaf(pd.x, s7, c0[7]);  c1[7] = fmaf(pd.y, s7, c1[7]);        \
  } while (0)

  LOADSET(0, q0); LOADSET(1, q0 + 1); LOADSET(2, q0 + 2); LOADSET(3, q0 + 3);

  for (int q = 0; q < NQH - 2; q += 4) {
    COMPUTE(0, q0 + q);     if (q + 4 < NQH) LOADSET(0, q0 + q + 4);
    COMPUTE(1, q0 + q + 1); if (q + 5 < NQH) LOADSET(1, q0 + q + 5);
    COMPUTE(2, q0 + q + 2); if (q + 6 < NQH) LOADSET(2, q0 + q + 6);
    COMPUTE(3, q0 + q + 3); if (q + 7 < NQH) LOADSET(3, q0 + q + 7);
  }
  // tail: NQH = 50 = 4*12 + 2 -> stages 0,1 hold q0+48, q0+49
  COMPUTE(0, q0 + NQH - 2);
  COMPUTE(1, q0 + NQH - 1);

  // ---- combine q-halves through LDS (conflict-free: stride-1 per j) ----
  const int col = r * 64 + lane;
  if (qh == 1) {
#pragma unroll
    for (int j = 0; j < 8; ++j) { part[j][col] = c0[j]; part[j + 8][col] = c1[j]; }
  }
  __syncthreads();
  if (qh == 0) {
#pragma unroll
    for (int j = 0; j < 8; ++j) { c0[j] += part[j][col]; c1[j] += part[j + 8][col]; }

    const int y  = 4 * k + r;
    const int x0 = 8 * lane;
    float* o0 = out + (((size_t)b * NC + 0) * HOUT + y) * WOUT + x0;
    float* o1 = out + (((size_t)b * NC + 1) * HOUT + y) * WOUT + x0;
    *(float4*)o0       = make_float4(c0[0], c0[1], c0[2], c0[3]);
    *(float4*)(o0 + 4) = make_float4(c0[4], c0[5], c0[6], c0[7]);
    *(float4*)o1       = make_float4(c1[0], c1[1], c1[2], c1[3]);
    *(float4*)(o1 + 4) = make_float4(c1[4], c1[5], c1[6], c1[7]);
  }
}

extern "C" void kernel_launch(void* const* d_in, const int* in_sizes, int n_in,
                              void* d_out, int out_size, void* d_ws, size_t ws_size,
                              hipStream_t stream) {
  const float* cls   = (const float*)d_in[0];   // [8,100,3] fp32
  const float* masks = (const float*)d_in[1];   // [8,100,128,128] fp32
  float* out = (float*)d_out;                   // [8,2,512,512] fp32
  dim3 grid(HIN, NB);   // 128 k-groups x 8 batches = 1024 blocks x 8 waves
  m2f_fused<<<grid, 512, 0, stream>>>(cls, masks, out);
}

// Round 8
// 147.610 us; speedup vs baseline: 1.7324x; 1.7324x over previous
//
#include <hip/hip_runtime.h>
#include <math.h>

#define NB 8
#define NQ 100
#define NCP1 3
#define NC 2
#define HIN 128
#define WIN 128
#define HOUT 512
#define WOUT 512
#define QSTR (HIN * WIN)

#if __has_builtin(__builtin_amdgcn_exp2f)
#define EXP2F(x) __builtin_amdgcn_exp2f(x)
#else
#define EXP2F(x) exp2f(x)
#endif
#if __has_builtin(__builtin_amdgcn_rcpf)
#define RCPF(x) __builtin_amdgcn_rcpf(x)
#else
#define RCPF(x) (1.0f / (x))
#endif

// R8: R6's wave-per-row layout (wave = output row y=4k+r; lane owns 8 px)
// but the halo comes IN-REGISTER: lane loads float4 at clamped col 2c-1 of
// rows rlo,rhi (2 VMEM/q, 4B-aligned unaligned loads — HW-supported), so the
// ds_bpermute latency chain that caused R6's 37% stall is gone.  Edge lanes
// (0 and 63) fixed by 6 lane-constant cndmasks on the vlerped values.
// Depth-4 pipeline (8 VGPR/stage), 256 thr, launch_bounds(256,4): VGPR cap
// 128 — no spill (R3/R7 lesson: this kernel needs ~60 VGPRs; tighter caps
// spill to scratch and blow up FETCH/WRITE).
__global__ __launch_bounds__(256, 4)
void m2f_fused(const float* __restrict__ cls,
               const float* __restrict__ masks,
               float* __restrict__ out) {
  const int k   = blockIdx.x;   // 0..127
  const int b   = blockIdx.y;   // 0..7
  const int tid = threadIdx.x;  // 0..255

  __shared__ float2 pq[NQ];     // (p_class0, p_class1) per q

  // ---- inline class softmax (keep first NC of NCP1) ----
  if (tid < NQ) {
    const float* cl = cls + (b * NQ + tid) * NCP1;
    float a0 = cl[0], a1 = cl[1], a2 = cl[2];
    float mx = fmaxf(a0, fmaxf(a1, a2));
    const float L2E = 1.4426950408889634f;
    float e0 = EXP2F((a0 - mx) * L2E);
    float e1 = EXP2F((a1 - mx) * L2E);
    float e2 = EXP2F((a2 - mx) * L2E);
    float inv = RCPF(e0 + e1 + e2);
    pq[tid] = make_float2(e0 * inv, e1 * inv);
  }
  __syncthreads();   // the only barrier

  const int r    = tid >> 6;    // wave id = output row phase 0..3 (y = 4k+r)
  const int lane = tid & 63;    // col group: x = 8*lane .. 8*lane+7

  // clamped input rows + vertical weights (pre-scaled by -log2e so
  // sigmoid(x) = rcp(1 + exp2(v)), v = -log2e * x)
  const int rlo = (r < 2) ? (k > 0 ? k - 1 : 0) : k;
  const int rhi = (r < 2) ? k : (k < HIN - 1 ? k + 1 : HIN - 1);
  const float NL2E = -1.4426950408889634f;
  const float wlo = ((r == 0) ? 0.375f : (r == 1) ? 0.125f
                   : (r == 2) ? 0.875f : 0.625f) * NL2E;
  const float whi = ((r == 0) ? 0.625f : (r == 1) ? 0.875f
                   : (r == 2) ? 0.125f : 0.375f) * NL2E;

  // load window: cols bcol..bcol+3 where bcol = clamp(2*lane-1, 0, 124).
  // lanes 1..62: {2c-1,2c,2c+1,2c+2} (exactly the needed halo window)
  // lane 0:      {0,1,2,3}    -> (tL,t0,t1,tR) = (T.x,T.x,T.y,T.z)
  // lane 63:     {124..127}   -> (tL,t0,t1,tR) = (T.y,T.z,T.w,T.w)
  const int bcol = (lane == 0) ? 0 : (lane == 63 ? WIN - 4 : 2 * lane - 1);
  const int oA = rlo * WIN + bcol;
  const int oB = rhi * WIN + bcol;
  const bool edgeL = (lane == 0);
  const bool edgeR = (lane == 63);

  const float* __restrict__ base = masks + (size_t)b * NQ * QSTR;  // uniform

  float c0[8], c1[8];
#pragma unroll
  for (int j = 0; j < 8; ++j) { c0[j] = 0.f; c1[j] = 0.f; }

  // depth-4 pipeline: 2 x float4 per stage
  float4 A0, B0, A1, B1, A2, B2, A3, B3;

#define LOADSET(S, qq)                                                    \
  do {                                                                    \
    const float* mq = base + (size_t)(qq) * QSTR; /* uniform SGPR adv */  \
    A##S = *(const float4*)(mq + oA);                                     \
    B##S = *(const float4*)(mq + oB);                                     \
  } while (0)

#define COMPUTE(S, qq)                                                    \
  do {                                                                    \
    const float2 pd = pq[qq];                                             \
    /* vertical lerp on the 4 loaded cols (pre-scaled by -log2e) */       \
    float Tx = fmaf(wlo, A##S.x, whi * B##S.x);                           \
    float Ty = fmaf(wlo, A##S.y, whi * B##S.y);                           \
    float Tz = fmaf(wlo, A##S.z, whi * B##S.z);                           \
    float Tw = fmaf(wlo, A##S.w, whi * B##S.w);                           \
    /* edge remap (lane-constant masks -> 6 cndmasks, no latency) */      \
    float tL = edgeR ? Ty : Tx;                                           \
    float t0 = edgeL ? Tx : (edgeR ? Tz : Ty);                            \
    float t1 = edgeL ? Ty : (edgeR ? Tw : Tz);                            \
    float tR = edgeL ? Tz : Tw;                                           \
    /* horizontal lerp, diff form */                                      \
    float dm = tL - t0, dd = t1 - t0, dp = tR - t1;                       \
    float v0 = fmaf(0.375f, dm, t0);                                      \
    float v1 = fmaf(0.125f, dm, t0);                                      \
    float v2 = fmaf(0.125f, dd, t0);                                      \
    float v3 = fmaf(0.375f, dd, t0);                                      \
    float v4 = fmaf(0.625f, dd, t0);                                      \
    float v5 = fmaf(0.875f, dd, t0);                                      \
    float v6 = fmaf(0.125f, dp, t1);                                      \
    float v7 = fmaf(0.375f, dp, t1);                                      \
    /* sigmoid per pixel (independent chains) */                          \
    float s0 = RCPF(1.0f + EXP2F(v0));                                    \
    float s1 = RCPF(1.0f + EXP2F(v1));                                    \
    float s2 = RCPF(1.0f + EXP2F(v2));                                    \
    float s3 = RCPF(1.0f + EXP2F(v3));                                    \
    float s4 = RCPF(1.0f + EXP2F(v4));                                    \
    float s5 = RCPF(1.0f + EXP2F(v5));                                    \
    float s6 = RCPF(1.0f + EXP2F(v6));                                    \
    float s7 = RCPF(1.0f + EXP2F(v7));                                    \
    c0[0] = fmaf(pd.x, s0, c0[0]);  c1[0] = fmaf(pd.y, s0, c1[0]);        \
    c0[1] = fmaf(pd.x, s1, c0[1]);  c1[1] = fmaf(pd.y, s1, c1[1]);        \
    c0[2] = fmaf(pd.x, s2, c0[2]);  c1[2] = fmaf(pd.y, s2, c1[2]);        \
    c0[3] = fmaf(pd.x, s3, c0[3]);  c1[3] = fmaf(pd.y, s3, c1[3]);        \
    c0[4] = fmaf(pd.x, s4, c0[4]);  c1[4] = fmaf(pd.y, s4, c1[4]);        \
    c0[5] = fmaf(pd.x, s5, c0[5]);  c1[5] = fmaf(pd.y, s5, c1[5]);        \
    c0[6] = fmaf(pd.x, s6, c0[6]);  c1[6] = fmaf(pd.y, s6, c1[6]);        \
    c0[7] = fmaf(pd.x, s7, c0[7]);  c1[7] = fmaf(pd.y, s7, c1[7]);        \
  } while (0)

  LOADSET(0, 0); LOADSET(1, 1); LOADSET(2, 2); LOADSET(3, 3);

  for (int q = 0; q < NQ; q += 4) {
    COMPUTE(0, q);     if (q + 4 < NQ) LOADSET(0, q + 4);
    COMPUTE(1, q + 1); if (q + 5 < NQ) LOADSET(1, q + 5);
    COMPUTE(2, q + 2); if (q + 6 < NQ) LOADSET(2, q + 6);
    COMPUTE(3, q + 3); if (q + 7 < NQ) LOADSET(3, q + 7);
  }

  // ---- stores: row y = 4k+r, cols 8*lane..8*lane+7, both classes ----
  const int y  = 4 * k + r;
  const int x0 = 8 * lane;
  float* o0 = out + (((size_t)b * NC + 0) * HOUT + y) * WOUT + x0;
  float* o1 = out + (((size_t)b * NC + 1) * HOUT + y) * WOUT + x0;
  *(float4*)o0       = make_float4(c0[0], c0[1], c0[2], c0[3]);
  *(float4*)(o0 + 4) = make_float4(c0[4], c0[5], c0[6], c0[7]);
  *(float4*)o1       = make_float4(c1[0], c1[1], c1[2], c1[3]);
  *(float4*)(o1 + 4) = make_float4(c1[4], c1[5], c1[6], c1[7]);
}

extern "C" void kernel_launch(void* const* d_in, const int* in_sizes, int n_in,
                              void* d_out, int out_size, void* d_ws, size_t ws_size,
                              hipStream_t stream) {
  const float* cls   = (const float*)d_in[0];   // [8,100,3] fp32
  const float* masks = (const float*)d_in[1];   // [8,100,128,128] fp32
  float* out = (float*)d_out;                   // [8,2,512,512] fp32
  dim3 grid(HIN, NB);   // 128 k-groups x 8 batches = 1024 blocks
  m2f_fused<<<grid, 256, 0, stream>>>(cls, masks, out);
}

// Round 9
// 132.854 us; speedup vs baseline: 1.9248x; 1.1111x over previous
//
#include <hip/hip_runtime.h>
#include <math.h>

#define NB 8
#define NQ 100
#define NQH 50
#define NCP1 3
#define NC 2
#define HIN 128
#define WIN 128
#define HOUT 512
#define WOUT 512
#define QSTR (HIN * WIN)

#if __has_builtin(__builtin_amdgcn_exp2f)
#define EXP2F(x) __builtin_amdgcn_exp2f(x)
#else
#define EXP2F(x) exp2f(x)
#endif
#if __has_builtin(__builtin_amdgcn_rcpf)
#define RCPF(x) __builtin_amdgcn_rcpf(x)
#else
#define RCPF(x) (1.0f / (x))
#endif

__device__ __forceinline__ float bperm(int byteaddr, float v) {
  return __int_as_float(__builtin_amdgcn_ds_bpermute(byteaddr, __float_as_int(v)));
}

// R9 = R7's q-split with the VGPR cap fixed.  R7 failed ONLY because
// __launch_bounds__(512,8) capped VGPR at 32 -> full spill (FETCH 76->319MB).
// R6's body needs ~40 VGPR, so (512,4) (cap 128) lets the allocator pick
// ~40-52 and 8 waves/SIMD become RESIDENT anyway (bounds constrain the
// allocator, not achieved occupancy): 4 blocks/CU x 8 waves = 32 waves/CU.
// Structure: 512 thr = 8 waves; wave w = row-phase r=w&3, q-half qh=w>>2
// (50 q each).  Wave = full output row: 2 coalesced float2 loads/q, halo via
// ds_bpermute (R8 proved the float4-halo variant costs MORE issue), depth-4
// pipeline, partials combined via 16KB conflict-free LDS, no atomics.
__global__ __launch_bounds__(512, 4)
void m2f_fused(const float* __restrict__ cls,
               const float* __restrict__ masks,
               float* __restrict__ out) {
  const int k   = blockIdx.x;   // 0..127
  const int b   = blockIdx.y;   // 0..7
  const int tid = threadIdx.x;  // 0..511

  __shared__ float2 pq[NQ];           // (p_class0, p_class1) per q
  __shared__ float  part[16][256];    // qh=1 partials: [j][r*64+lane]

  // ---- inline class softmax (keep first NC of NCP1) ----
  if (tid < NQ) {
    const float* cl = cls + (b * NQ + tid) * NCP1;
    float a0 = cl[0], a1 = cl[1], a2 = cl[2];
    float mx = fmaxf(a0, fmaxf(a1, a2));
    const float L2E = 1.4426950408889634f;
    float e0 = EXP2F((a0 - mx) * L2E);
    float e1 = EXP2F((a1 - mx) * L2E);
    float e2 = EXP2F((a2 - mx) * L2E);
    float inv = RCPF(e0 + e1 + e2);
    pq[tid] = make_float2(e0 * inv, e1 * inv);
  }
  __syncthreads();

  const int wave = tid >> 6;    // 0..7
  const int r    = wave & 3;    // output row phase (y = 4k+r)
  const int qh   = wave >> 2;   // q half: 0 -> q 0..49, 1 -> q 50..99
  const int lane = tid & 63;    // col group: x = 8*lane .. 8*lane+7
  const int q0   = qh * NQH;

  // clamped input rows + vertical weights (pre-scaled by -log2e so
  // sigmoid(x) = rcp(1 + exp2(v)), v = -log2e * x)
  const int rlo = (r < 2) ? (k > 0 ? k - 1 : 0) : k;
  const int rhi = (r < 2) ? k : (k < HIN - 1 ? k + 1 : HIN - 1);
  const float NL2E = -1.4426950408889634f;
  const float wlo = ((r == 0) ? 0.375f : (r == 1) ? 0.125f
                   : (r == 2) ? 0.875f : 0.625f) * NL2E;
  const float whi = ((r == 0) ? 0.625f : (r == 1) ? 0.875f
                   : (r == 2) ? 0.125f : 0.375f) * NL2E;

  const int oA = rlo * WIN + 2 * lane;
  const int oB = rhi * WIN + 2 * lane;
  const float* __restrict__ base = masks + (size_t)b * NQ * QSTR;  // uniform

  const int addrL = (lane - 1) << 2;
  const int addrR = (lane + 1) << 2;
  const bool edgeL = (lane == 0);
  const bool edgeR = (lane == 63);

  float c0[8], c1[8];
#pragma unroll
  for (int j = 0; j < 8; ++j) { c0[j] = 0.f; c1[j] = 0.f; }

  // depth-4 pipeline: 2 x float2 per stage
  float2 A0, B0, A1, B1, A2, B2, A3, B3;

#define LOADSET(S, qq)                                                    \
  do {                                                                    \
    const float* mq = base + (size_t)(qq) * QSTR; /* uniform SGPR adv */  \
    A##S = *(const float2*)(mq + oA);                                     \
    B##S = *(const float2*)(mq + oB);                                     \
  } while (0)

#define COMPUTE(S, qq)                                                    \
  do {                                                                    \
    const float2 pd = pq[qq];                                             \
    float t0 = fmaf(wlo, A##S.x, whi * B##S.x);   /* col 2c   */          \
    float t1 = fmaf(wlo, A##S.y, whi * B##S.y);   /* col 2c+1 */          \
    float tLr = bperm(addrL, t1);                                         \
    float tRr = bperm(addrR, t0);                                         \
    float tL = edgeL ? t0 : tLr;                                          \
    float tR = edgeR ? t1 : tRr;                                          \
    float dm = tL - t0, dd = t1 - t0, dp = tR - t1;                       \
    float v0 = fmaf(0.375f, dm, t0);                                      \
    float v1 = fmaf(0.125f, dm, t0);                                      \
    float v2 = fmaf(0.125f, dd, t0);                                      \
    float v3 = fmaf(0.375f, dd, t0);                                      \
    float v4 = fmaf(0.625f, dd, t0);                                      \
    float v5 = fmaf(0.875f, dd, t0);                                      \
    float v6 = fmaf(0.125f, dp, t1);                                      \
    float v7 = fmaf(0.375f, dp, t1);                                      \
    float s0 = RCPF(1.0f + EXP2F(v0));                                    \
    float s1 = RCPF(1.0f + EXP2F(v1));                                    \
    float s2 = RCPF(1.0f + EXP2F(v2));                                    \
    float s3 = RCPF(1.0f + EXP2F(v3));                                    \
    float s4 = RCPF(1.0f + EXP2F(v4));                                    \
    float s5 = RCPF(1.0f + EXP2F(v5));                                    \
    float s6 = RCPF(1.0f + EXP2F(v6));                                    \
    float s7 = RCPF(1.0f + EXP2F(v7));                                    \
    c0[0] = fmaf(pd.x, s0, c0[0]);  c1[0] = fmaf(pd.y, s0, c1[0]);        \
    c0[1] = fmaf(pd.x, s1, c0[1]);  c1[1] = fmaf(pd.y, s1, c1[1]);        \
    c0[2] = fmaf(pd.x, s2, c0[2]);  c1[2] = fmaf(pd.y, s2, c1[2]);        \
    c0[3] = fmaf(pd.x, s3, c0[3]);  c1[3] = fmaf(pd.y, s3, c1[3]);        \
    c0[4] = fmaf(pd.x, s4, c0[4]);  c1[4] = fmaf(pd.y, s4, c1[4]);        \
    c0[5] = fmaf(pd.x, s5, c0[5]);  c1[5] = fmaf(pd.y, s5, c1[5]);        \
    c0[6] = fmaf(pd.x, s6, c0[6]);  c1[6] = fmaf(pd.y, s6, c1[6]);        \
    c0[7] = fmaf(pd.x, s7, c0[7]);  c1[7] = fmaf(pd.y, s7, c1[7]);        \
  } while (0)

  LOADSET(0, q0); LOADSET(1, q0 + 1); LOADSET(2, q0 + 2); LOADSET(3, q0 + 3);

  for (int q = 0; q < NQH - 2; q += 4) {
    COMPUTE(0, q0 + q);     if (q + 4 < NQH) LOADSET(0, q0 + q + 4);
    COMPUTE(1, q0 + q + 1); if (q + 5 < NQH) LOADSET(1, q0 + q + 5);
    COMPUTE(2, q0 + q + 2); if (q + 6 < NQH) LOADSET(2, q0 + q + 6);
    COMPUTE(3, q0 + q + 3); if (q + 7 < NQH) LOADSET(3, q0 + q + 7);
  }
  // tail: NQH = 50 = 4*12 + 2 -> stages 0,1 hold q0+48, q0+49
  COMPUTE(0, q0 + NQH - 2);
  COMPUTE(1, q0 + NQH - 1);

  // ---- combine q-halves through LDS (conflict-free: stride-1 per j) ----
  const int col = r * 64 + lane;
  if (qh == 1) {
#pragma unroll
    for (int j = 0; j < 8; ++j) { part[j][col] = c0[j]; part[j + 8][col] = c1[j]; }
  }
  __syncthreads();
  if (qh == 0) {
#pragma unroll
    for (int j = 0; j < 8; ++j) { c0[j] += part[j][col]; c1[j] += part[j + 8][col]; }

    const int y  = 4 * k + r;
    const int x0 = 8 * lane;
    float* o0 = out + (((size_t)b * NC + 0) * HOUT + y) * WOUT + x0;
    float* o1 = out + (((size_t)b * NC + 1) * HOUT + y) * WOUT + x0;
    *(float4*)o0       = make_float4(c0[0], c0[1], c0[2], c0[3]);
    *(float4*)(o0 + 4) = make_float4(c0[4], c0[5], c0[6], c0[7]);
    *(float4*)o1       = make_float4(c1[0], c1[1], c1[2], c1[3]);
    *(float4*)(o1 + 4) = make_float4(c1[4], c1[5], c1[6], c1[7]);
  }
}

extern "C" void kernel_launch(void* const* d_in, const int* in_sizes, int n_in,
                              void* d_out, int out_size, void* d_ws, size_t ws_size,
                              hipStream_t stream) {
  const float* cls   = (const float*)d_in[0];   // [8,100,3] fp32
  const float* masks = (const float*)d_in[1];   // [8,100,128,128] fp32
  float* out = (float*)d_out;                   // [8,2,512,512] fp32
  dim3 grid(HIN, NB);   // 128 k-groups x 8 batches, 8 waves/block
  m2f_fused<<<grid, 512, 0, stream>>>(cls, masks, out);
}